// Round 1
// baseline (26556.998 us; speedup 1.0000x reference)
//
#include <hip/hip_runtime.h>

// ResidualSkipRNNForecaster — MI355X persistent-RNN implementation.
//
// Structure: B=128 independent recurrence chains -> 1 block per batch row,
// 128 blocks x 512 threads, NO inter-block sync. Each block loops t=0..1023:
//   L0: a = x_t@Wi0 + h0@Wh0 + (bi0+bh0); v2 = tanh(a)+h0; h0 = LN(v2)*g0+be0
//   L1: a = h0@Wi1 + h1@Wh1 + (bi1+bh1);  v2 = tanh(a)+h1; h1 = LN(v2)*g1+be1
// Weights converted once per launch to bf16 (RNE) into d_ws -> halves the
// per-step weight stream (1.64 MB/block/step), which is the binding resource
// (per-CU L1/L2 load BW ~60-128 B/cy). State/accumulation stays fp32.
//
// Thread map inside a block (512 threads): tid = ksub*64 + oct.
//   oct  (0..63): column octet -> cols [8*oct, 8*oct+8), loaded as one uint4
//   ksub (0..7) : k-slice [64*ksub, 64*ksub+64) of the dot product
// Partials combined through LDS; then thread c==tid owns column c for
// bias/tanh/residual/LN epilogue.

#define B_SZ 128
#define T_SZ 1024
#define DD   64
#define HH   512

__device__ __forceinline__ unsigned short f2b(float f) {
  unsigned u = __float_as_uint(f);
  u += 0x7fffu + ((u >> 16) & 1u);   // round-to-nearest-even
  return (unsigned short)(u >> 16);
}

__global__ void prep_kernel(const float* __restrict__ Wi0, const float* __restrict__ Wh0,
                            const float* __restrict__ Wi1, const float* __restrict__ Wh1,
                            const float* __restrict__ bi0, const float* __restrict__ bh0,
                            const float* __restrict__ bi1, const float* __restrict__ bh1,
                            unsigned short* __restrict__ wi0, unsigned short* __restrict__ wh0,
                            unsigned short* __restrict__ wi1, unsigned short* __restrict__ wh1,
                            float* __restrict__ b0, float* __restrict__ b1) {
  int g = blockIdx.x * blockDim.x + threadIdx.x;
  int stride = gridDim.x * blockDim.x;
  for (int i = g; i < DD * HH; i += stride) wi0[i] = f2b(Wi0[i]);
  for (int i = g; i < HH * HH; i += stride) wh0[i] = f2b(Wh0[i]);
  for (int i = g; i < HH * HH; i += stride) wi1[i] = f2b(Wi1[i]);
  for (int i = g; i < HH * HH; i += stride) wh1[i] = f2b(Wh1[i]);
  for (int i = g; i < HH; i += stride) { b0[i] = bi0[i] + bh0[i]; b1[i] = bi1[i] + bh1[i]; }
}

__device__ __forceinline__ void fma8(float acc[8], uint4 w, float h) {
  // uint = two bf16: low ushort = even col, high ushort = odd col
  acc[0] = fmaf(h, __uint_as_float(w.x << 16), acc[0]);
  acc[1] = fmaf(h, __uint_as_float(w.x & 0xffff0000u), acc[1]);
  acc[2] = fmaf(h, __uint_as_float(w.y << 16), acc[2]);
  acc[3] = fmaf(h, __uint_as_float(w.y & 0xffff0000u), acc[3]);
  acc[4] = fmaf(h, __uint_as_float(w.z << 16), acc[4]);
  acc[5] = fmaf(h, __uint_as_float(w.z & 0xffff0000u), acc[5]);
  acc[6] = fmaf(h, __uint_as_float(w.w << 16), acc[6]);
  acc[7] = fmaf(h, __uint_as_float(w.w & 0xffff0000u), acc[7]);
}

__global__ __launch_bounds__(512) void rnn_persist(
    const float* __restrict__ x,
    const uint4* __restrict__ wi0, const uint4* __restrict__ wh0,
    const uint4* __restrict__ wi1, const uint4* __restrict__ wh1,
    const float* __restrict__ b0g, const float* __restrict__ b1g,
    const float* __restrict__ g0, const float* __restrict__ be0,
    const float* __restrict__ g1, const float* __restrict__ be1,
    const float* __restrict__ wfc, const float* __restrict__ bfc,
    float* __restrict__ out) {
  const int b   = blockIdx.x;
  const int tid = threadIdx.x;
  const int oct = tid & 63;
  const int ks  = tid >> 6;
  const int c   = tid;          // column owned in the epilogue phase

  __shared__ __align__(16) float h0s[HH];
  __shared__ __align__(16) float h1s[HH];
  __shared__ __align__(16) float xs[DD];
  __shared__ __align__(16) float part[8][HH];   // 16 KB partial sums
  __shared__ float wred[8][2];
  __shared__ float stats[2];                    // mu, rstd broadcast

  // per-column constants held in registers for the whole T loop
  const float b0c = b0g[c], b1c = b1g[c];
  const float g0c = g0[c], be0c = be0[c];
  const float g1c = g1[c], be1c = be1[c];
  const float wfcc = wfc[c];

  h0s[tid] = 0.f;
  h1s[tid] = 0.f;
  __syncthreads();

  const float* xrow = x + (size_t)b * T_SZ * DD;

  for (int t = 0; t < T_SZ; ++t) {
    if (tid < DD) xs[tid] = xrow[t * DD + tid];
    __syncthreads();

    // ================= layer 0: x@Wi0 + h0@Wh0 =================
    float acc[8];
#pragma unroll
    for (int j = 0; j < 8; ++j) acc[j] = 0.f;
    {
      const uint4* wp = wi0 + (size_t)(ks * 8) * 64 + oct;
      const float4* hv4 = (const float4*)&xs[ks * 8];
#pragma unroll
      for (int k4 = 0; k4 < 2; ++k4) {
        float4 hv = hv4[k4];
        fma8(acc, wp[(k4 * 4 + 0) * 64], hv.x);
        fma8(acc, wp[(k4 * 4 + 1) * 64], hv.y);
        fma8(acc, wp[(k4 * 4 + 2) * 64], hv.z);
        fma8(acc, wp[(k4 * 4 + 3) * 64], hv.w);
      }
    }
    {
      const uint4* wp = wh0 + (size_t)(ks * 64) * 64 + oct;
      const float4* hv4 = (const float4*)&h0s[ks * 64];
#pragma unroll 4
      for (int k4 = 0; k4 < 16; ++k4) {
        float4 hv = hv4[k4];
        fma8(acc, wp[(k4 * 4 + 0) * 64], hv.x);
        fma8(acc, wp[(k4 * 4 + 1) * 64], hv.y);
        fma8(acc, wp[(k4 * 4 + 2) * 64], hv.z);
        fma8(acc, wp[(k4 * 4 + 3) * 64], hv.w);
      }
    }
    *(float4*)&part[ks][oct * 8]     = make_float4(acc[0], acc[1], acc[2], acc[3]);
    *(float4*)&part[ks][oct * 8 + 4] = make_float4(acc[4], acc[5], acc[6], acc[7]);
    __syncthreads();

    {
      float v = b0c;
#pragma unroll
      for (int p = 0; p < 8; ++p) v += part[p][c];
      float cand = tanhf(v);
      float v2 = cand + h0s[c];              // residual with OLD h0
      float s = v2, q = v2 * v2;
#pragma unroll
      for (int off = 32; off; off >>= 1) { s += __shfl_down(s, off); q += __shfl_down(q, off); }
      if ((tid & 63) == 0) { wred[tid >> 6][0] = s; wred[tid >> 6][1] = q; }
      __syncthreads();
      if (tid == 0) {
        float S = 0.f, Q = 0.f;
#pragma unroll
        for (int w = 0; w < 8; ++w) { S += wred[w][0]; Q += wred[w][1]; }
        float mu = S * (1.f / HH);
        float var = Q * (1.f / HH) - mu * mu;
        stats[0] = mu; stats[1] = 1.f / sqrtf(var + 1e-5f);
      }
      __syncthreads();
      h0s[c] = (v2 - stats[0]) * stats[1] * g0c + be0c;   // new h0
      __syncthreads();
    }

    // ================= layer 1: h0n@Wi1 + h1@Wh1 =================
#pragma unroll
    for (int j = 0; j < 8; ++j) acc[j] = 0.f;
    {
      const uint4* wp = wi1 + (size_t)(ks * 64) * 64 + oct;
      const float4* hv4 = (const float4*)&h0s[ks * 64];
#pragma unroll 4
      for (int k4 = 0; k4 < 16; ++k4) {
        float4 hv = hv4[k4];
        fma8(acc, wp[(k4 * 4 + 0) * 64], hv.x);
        fma8(acc, wp[(k4 * 4 + 1) * 64], hv.y);
        fma8(acc, wp[(k4 * 4 + 2) * 64], hv.z);
        fma8(acc, wp[(k4 * 4 + 3) * 64], hv.w);
      }
    }
    {
      const uint4* wp = wh1 + (size_t)(ks * 64) * 64 + oct;
      const float4* hv4 = (const float4*)&h1s[ks * 64];
#pragma unroll 4
      for (int k4 = 0; k4 < 16; ++k4) {
        float4 hv = hv4[k4];
        fma8(acc, wp[(k4 * 4 + 0) * 64], hv.x);
        fma8(acc, wp[(k4 * 4 + 1) * 64], hv.y);
        fma8(acc, wp[(k4 * 4 + 2) * 64], hv.z);
        fma8(acc, wp[(k4 * 4 + 3) * 64], hv.w);
      }
    }
    *(float4*)&part[ks][oct * 8]     = make_float4(acc[0], acc[1], acc[2], acc[3]);
    *(float4*)&part[ks][oct * 8 + 4] = make_float4(acc[4], acc[5], acc[6], acc[7]);
    __syncthreads();

    {
      float v = b1c;
#pragma unroll
      for (int p = 0; p < 8; ++p) v += part[p][c];
      float cand = tanhf(v);
      float v2 = cand + h1s[c];              // residual with OLD h1
      float s = v2, q = v2 * v2;
#pragma unroll
      for (int off = 32; off; off >>= 1) { s += __shfl_down(s, off); q += __shfl_down(q, off); }
      if ((tid & 63) == 0) { wred[tid >> 6][0] = s; wred[tid >> 6][1] = q; }
      __syncthreads();
      if (tid == 0) {
        float S = 0.f, Q = 0.f;
#pragma unroll
        for (int w = 0; w < 8; ++w) { S += wred[w][0]; Q += wred[w][1]; }
        float mu = S * (1.f / HH);
        float var = Q * (1.f / HH) - mu * mu;
        stats[0] = mu; stats[1] = 1.f / sqrtf(var + 1e-5f);
      }
      __syncthreads();
      h1s[c] = (v2 - stats[0]) * stats[1] * g1c + be1c;   // new h1
      __syncthreads();
    }
  }

  // ================= head: out[b] = h1 . Wfc + bfc =================
  {
    float s = h1s[c] * wfcc;
#pragma unroll
    for (int off = 32; off; off >>= 1) s += __shfl_down(s, off);
    if ((tid & 63) == 0) wred[tid >> 6][0] = s;
    __syncthreads();
    if (tid == 0) {
      float S = 0.f;
#pragma unroll
      for (int w = 0; w < 8; ++w) S += wred[w][0];
      out[b] = S + bfc[0];
    }
  }
}

extern "C" void kernel_launch(void* const* d_in, const int* in_sizes, int n_in,
                              void* d_out, int out_size, void* d_ws, size_t ws_size,
                              hipStream_t stream) {
  const float* x   = (const float*)d_in[0];
  const float* Wi0 = (const float*)d_in[1];
  const float* bi0 = (const float*)d_in[2];
  const float* Wh0 = (const float*)d_in[3];
  const float* bh0 = (const float*)d_in[4];
  const float* g0  = (const float*)d_in[5];
  const float* be0 = (const float*)d_in[6];
  const float* Wi1 = (const float*)d_in[7];
  const float* bi1 = (const float*)d_in[8];
  const float* Wh1 = (const float*)d_in[9];
  const float* bh1 = (const float*)d_in[10];
  const float* g1  = (const float*)d_in[11];
  const float* be1 = (const float*)d_in[12];
  const float* Wfc = (const float*)d_in[13];
  const float* bfc = (const float*)d_in[14];
  float* out = (float*)d_out;

  // workspace layout (bf16 weights + combined biases), ~1.57 MB total
  char* ws = (char*)d_ws;
  unsigned short* wi0 = (unsigned short*)(ws);                        //  64*512*2 = 65536 B
  unsigned short* wh0 = (unsigned short*)(ws + 65536);                // 512*512*2 = 524288 B
  unsigned short* wi1 = (unsigned short*)(ws + 65536 + 524288);       // 524288 B
  unsigned short* wh1 = (unsigned short*)(ws + 65536 + 2 * 524288);   // 524288 B
  float* b0 = (float*)(ws + 65536 + 3 * 524288);                      // 2048 B
  float* b1 = (float*)(ws + 65536 + 3 * 524288 + 2048);               // 2048 B

  prep_kernel<<<256, 256, 0, stream>>>(Wi0, Wh0, Wi1, Wh1, bi0, bh0, bi1, bh1,
                                       wi0, wh0, wi1, wh1, b0, b1);
  rnn_persist<<<B_SZ, 512, 0, stream>>>(x, (const uint4*)wi0, (const uint4*)wh0,
                                        (const uint4*)wi1, (const uint4*)wh1,
                                        b0, b1, g0, be0, g1, be1, Wfc, bfc, out);
}

// Round 2
// 16336.168 us; speedup vs baseline: 1.6257x; 1.6257x over previous
//
#include <hip/hip_runtime.h>

// ResidualSkipRNNForecaster — MI355X pair-split persistent RNN.
//
// 128 chains (batch rows) x 1024 sequential steps. Round-1 lesson: a block
// owning all 512 columns must stream 1.64 MB of bf16 weights per step through
// one CU's load port (~60 B/cy) -> >=11 ms floor, and only 128 CUs active.
//
// This version: 2 blocks per chain (256 blocks x 512 threads), each owns 256
// output columns -> 800 KB/step/CU weight stream, all 256 CUs busy.
// LayerNorm is folded into the following matmuls so the cross-block exchange
// is the PRE-LN candidate v2 (h_new = (v2-mu)*rstd*g+be is linear in v2):
//   z_next[c] = rstd*(v2 @ (g.*W))[c] - rstd*mu*u[c] + q[c],
//   u[c]=sum_j g[j]W[j,c], q[c]=sum_j be[j]W[j,c]  (precomputed, exact here).
// So each block starts its big matmuls on locally-available data and only
// needs the partner's v2-half (+ sum/sumsq partials) late -> publish latency
// hides under ~10K cycles of compute. Exchange protocol: monotonic token
// flags (no re-init races), agent-scope release/acquire atomics, payload as
// relaxed agent-scope 8B atomics (cross-XCD safe). Flags zeroed by prep each
// launch (d_ws is re-poisoned to 0xAA before every timed call).
//
// Thread map (512 thr): oct = tid&31 -> col octet (8 cols via one uint4 row
// chunk), ks = tid>>5 -> k-slice of 32 (16 slices cover k=512). Partials
// combined through LDS part[16][256]; epilogue thread c<256 owns local col c.

#define T_SZ 1024
#define DD   64
#define HH   512

__device__ __forceinline__ unsigned short f2b(float f) {
  unsigned u = __float_as_uint(f);
  u += 0x7fffu + ((u >> 16) & 1u);   // RNE
  return (unsigned short)(u >> 16);
}

__device__ __forceinline__ unsigned long long packf2(float a, float b) {
  return (unsigned long long)__float_as_uint(a) |
         ((unsigned long long)__float_as_uint(b) << 32);
}
__device__ __forceinline__ float unpack_lo(unsigned long long u) {
  return __uint_as_float((unsigned)u);
}
__device__ __forceinline__ float unpack_hi(unsigned long long u) {
  return __uint_as_float((unsigned)(u >> 32));
}

__device__ __forceinline__ void st_rlx(unsigned long long* p, unsigned long long v) {
  __hip_atomic_store(p, v, __ATOMIC_RELAXED, __HIP_MEMORY_SCOPE_AGENT);
}
__device__ __forceinline__ unsigned long long ld_rlx(unsigned long long* p) {
  return __hip_atomic_load(p, __ATOMIC_RELAXED, __HIP_MEMORY_SCOPE_AGENT);
}

__global__ void prep_kernel(const float* __restrict__ Wi0, const float* __restrict__ Wh0,
                            const float* __restrict__ Wi1, const float* __restrict__ Wh1,
                            const float* __restrict__ bi0, const float* __restrict__ bh0,
                            const float* __restrict__ bi1, const float* __restrict__ bh1,
                            const float* __restrict__ g0, const float* __restrict__ be0,
                            const float* __restrict__ g1, const float* __restrict__ be1,
                            unsigned short* __restrict__ wi0b, unsigned short* __restrict__ wh0p,
                            unsigned short* __restrict__ wi1p, unsigned short* __restrict__ wh1p,
                            float* __restrict__ cvec, unsigned* __restrict__ flags) {
  int g = blockIdx.x * blockDim.x + threadIdx.x;
  int stride = gridDim.x * blockDim.x;
  for (int i = g; i < DD * HH; i += stride) wi0b[i] = f2b(Wi0[i]);
  for (int i = g; i < HH * HH; i += stride) {
    int j = i >> 9;
    wh0p[i] = f2b(g0[j] * Wh0[i]);   // fold LN gamma of the feeding state
    wi1p[i] = f2b(g0[j] * Wi1[i]);
    wh1p[i] = f2b(g1[j] * Wh1[i]);
  }
  if (g < HH) {
    float uw0 = 0.f, qw0 = 0.f, uw1 = 0.f, qw1 = 0.f, uh1 = 0.f, qh1 = 0.f;
    for (int j = 0; j < HH; ++j) {     // coalesced across g per j
      float a = Wh0[j * HH + g], b = Wi1[j * HH + g], d = Wh1[j * HH + g];
      uw0 += g0[j] * a; qw0 += be0[j] * a;
      uw1 += g0[j] * b; qw1 += be0[j] * b;
      uh1 += g1[j] * d; qh1 += be1[j] * d;
    }
    float b0 = bi0[g] + bh0[g], b1 = bi1[g] + bh1[g];
    cvec[0 * HH + g] = b0 + qw0;        // c0 full (t>0)
    cvec[1 * HH + g] = b0;              // c0 init (t==0, h0=0)
    cvec[2 * HH + g] = b1 + qw1 + qh1;  // c1 full
    cvec[3 * HH + g] = b1 + qw1;        // c1 init (h1=0 but h0n real)
    cvec[4 * HH + g] = uw0;
    cvec[5 * HH + g] = uw1;
    cvec[6 * HH + g] = uh1;
  }
  if (g < 256) flags[g * 32] = 0;       // one flag per block, 128B apart
}

__device__ __forceinline__ void fma8(float acc[8], uint4 w, float h) {
  acc[0] = fmaf(h, __uint_as_float(w.x << 16), acc[0]);
  acc[1] = fmaf(h, __uint_as_float(w.x & 0xffff0000u), acc[1]);
  acc[2] = fmaf(h, __uint_as_float(w.y << 16), acc[2]);
  acc[3] = fmaf(h, __uint_as_float(w.y & 0xffff0000u), acc[3]);
  acc[4] = fmaf(h, __uint_as_float(w.z << 16), acc[4]);
  acc[5] = fmaf(h, __uint_as_float(w.z & 0xffff0000u), acc[5]);
  acc[6] = fmaf(h, __uint_as_float(w.w << 16), acc[6]);
  acc[7] = fmaf(h, __uint_as_float(w.w & 0xffff0000u), acc[7]);
}

// k=512 matmul slice: this thread's 32 k-values against its 8 columns.
__device__ __forceinline__ void mm512(float acc[8], const uint4* __restrict__ wp,
                                      const float* __restrict__ v, int ksb) {
#pragma unroll 4
  for (int kk = 0; kk < 8; ++kk) {
    const int k = ksb + kk * 4;
    float4 hv = *(const float4*)&v[k];
    uint4 w0 = wp[(size_t)(k + 0) * 64];
    uint4 w1 = wp[(size_t)(k + 1) * 64];
    uint4 w2 = wp[(size_t)(k + 2) * 64];
    uint4 w3 = wp[(size_t)(k + 3) * 64];
    fma8(acc, w0, hv.x);
    fma8(acc, w1, hv.y);
    fma8(acc, w2, hv.z);
    fma8(acc, w3, hv.w);
  }
}

__global__ __launch_bounds__(512) void rnn_pair(
    const float* __restrict__ x,
    const uint4* __restrict__ wi0b, const uint4* __restrict__ wh0p,
    const uint4* __restrict__ wi1p, const uint4* __restrict__ wh1p,
    const float* __restrict__ cvec,
    const float* __restrict__ g0v, const float* __restrict__ be0v,
    const float* __restrict__ g1v, const float* __restrict__ be1v,
    const float* __restrict__ wfc, const float* __restrict__ bfc,
    unsigned long long* __restrict__ slots, unsigned* __restrict__ flags,
    float* __restrict__ out) {
  const int blk = blockIdx.x;
  const int chain = blk >> 1, p = blk & 1;
  const int tid = threadIdx.x;
  const int oct = tid & 31, ks = tid >> 5;
  const int ksb = ks * 32;
  unsigned long long* myslot = slots + (size_t)blk * 512;   // 4 KB/slot
  unsigned long long* pslot  = slots + (size_t)(blk ^ 1) * 512;
  unsigned* myflag = flags + blk * 32;
  unsigned* pflag  = flags + (blk ^ 1) * 32;

  __shared__ __align__(16) float v2a[HH];        // v2 of layer 0 (full)
  __shared__ __align__(16) float v2b[HH];        // v2 of layer 1 (full)
  __shared__ __align__(16) float xs[DD];
  __shared__ __align__(16) float part[16][256];  // 16 KB partials
  __shared__ float wred[4][2];
  __shared__ float wredH[8];
  __shared__ float sq0own[2], sq1own[2];

  v2a[tid] = 0.f;                                // t=0: h-feedback terms are
  v2b[tid] = 0.f;                                // multiplied by rstd_prev=0

  const int c  = tid & 255;                      // local epilogue column
  const int gc = p * 256 + c;                    // global column
  const float c0f = cvec[gc],            c0i = cvec[HH + gc];
  const float c1f = cvec[2 * HH + gc],   c1i = cvec[3 * HH + gc];
  const float uw0 = cvec[4 * HH + gc],   uw1 = cvec[5 * HH + gc];
  const float uh1 = cvec[6 * HH + gc];
  const float g0c = g0v[gc], be0c = be0v[gc];
  const float g1c = g1v[gc], be1c = be1v[gc];

  const uint4* wpi0 = wi0b + p * 32 + oct;
  const uint4* wph0 = wh0p + p * 32 + oct;
  const uint4* wpi1 = wi1p + p * 32 + oct;
  const uint4* wph1 = wh1p + p * 32 + oct;

  float r0p = 0.f, m0p = 0.f;        // layer-0 stats of previous step
  float h0prev = 0.f, h1prev = 0.f;  // own residual values (post-LN h)
  float v2own1 = 0.f;                // own v2_1 of current step (for h1prev)
  const float* xrow = x + (size_t)chain * T_SZ * DD;
  __syncthreads();

  for (int t = 0; t < T_SZ; ++t) {
    // ======== phase A : z0 = x@Wi0 + r0p*(v2a@Wh0') + consts ========
    if (tid < DD) xs[tid] = xrow[t * DD + tid];
    __syncthreads();

    float acc[8];
#pragma unroll
    for (int j = 0; j < 8; ++j) acc[j] = 0.f;
    mm512(acc, wph0, v2a, ksb);                  // h0-feedback (scaled below)
#pragma unroll
    for (int j = 0; j < 8; ++j) acc[j] *= r0p;
    {                                            // x @ Wi0 : k-slice of 4
      float4 hv = *(const float4*)&xs[ks * 4];
      uint4 w0 = wpi0[(size_t)(ks * 4 + 0) * 64];
      uint4 w1 = wpi0[(size_t)(ks * 4 + 1) * 64];
      uint4 w2 = wpi0[(size_t)(ks * 4 + 2) * 64];
      uint4 w3 = wpi0[(size_t)(ks * 4 + 3) * 64];
      fma8(acc, w0, hv.x); fma8(acc, w1, hv.y); fma8(acc, w2, hv.z); fma8(acc, w3, hv.w);
    }
    *(float4*)&part[ks][oct * 8]     = make_float4(acc[0], acc[1], acc[2], acc[3]);
    *(float4*)&part[ks][oct * 8 + 4] = make_float4(acc[4], acc[5], acc[6], acc[7]);
    __syncthreads();

    float v2own0 = 0.f;
    if (tid < 256) {
      float z = ((t == 0) ? c0i : c0f) - r0p * m0p * uw0;
#pragma unroll
      for (int i = 0; i < 16; ++i) z += part[i][c];
      v2own0 = tanhf(z) + h0prev;
      v2a[gc] = v2own0;                          // own half of new v2_0
      float s = v2own0, q = v2own0 * v2own0;
#pragma unroll
      for (int off = 32; off; off >>= 1) { s += __shfl_down(s, off); q += __shfl_down(q, off); }
      if ((tid & 63) == 0) { wred[tid >> 6][0] = s; wred[tid >> 6][1] = q; }
    }
    __syncthreads();
    // publish exchange 0: v2_0 own half + (sum,sumsq)
    if (tid < 128) {
      st_rlx(myslot + tid, packf2(v2a[p * 256 + tid * 2], v2a[p * 256 + tid * 2 + 1]));
    }
    if (tid == 0) {
      float S = wred[0][0] + wred[1][0] + wred[2][0] + wred[3][0];
      float Q = wred[0][1] + wred[1][1] + wred[2][1] + wred[3][1];
      sq0own[0] = S; sq0own[1] = Q;
      st_rlx(myslot + 128, packf2(S, Q));
    }
    __syncthreads();
    if (tid == 0)
      __hip_atomic_store(myflag, 2u * t + 1u, __ATOMIC_RELEASE, __HIP_MEMORY_SCOPE_AGENT);

    // ======== phase B : z1 = r0*(v2_0@Wi1') + r1p*(v2_1@Wh1') + consts ====
    // poll1: need partner v2_1^{t-1} (flag >= 2t; trivially true at t=0)
    if (tid == 0) {
      while (__hip_atomic_load(pflag, __ATOMIC_ACQUIRE, __HIP_MEMORY_SCOPE_AGENT) < 2u * t)
        __builtin_amdgcn_s_sleep(1);
    }
    __syncthreads();
    if (tid < 128) {
      unsigned long long u = ld_rlx(pslot + 256 + tid);
      v2b[(1 - p) * 256 + tid * 2]     = unpack_lo(u);
      v2b[(1 - p) * 256 + tid * 2 + 1] = unpack_hi(u);
    }
    float r1p = 0.f, m1p = 0.f;
    if (t > 0) {
      unsigned long long u = ld_rlx(pslot + 384);
      float S = unpack_lo(u) + sq1own[0], Q = unpack_hi(u) + sq1own[1];
      m1p = S * (1.f / HH);
      r1p = 1.f / sqrtf(Q * (1.f / HH) - m1p * m1p + 1e-5f);
    }
    if (tid < 256) h1prev = (t == 0) ? 0.f : (v2own1 - m1p) * r1p * g1c + be1c;
    __syncthreads();                              // v2b full now

    float accB[8], accB2[8];
#pragma unroll
    for (int j = 0; j < 8; ++j) { accB[j] = 0.f; accB2[j] = 0.f; }
    mm512(accB, wph1, v2b, ksb);                  // h1-feedback part

    // poll0: need partner v2_0^t (flag >= 2t+1)
    if (tid == 0) {
      while (__hip_atomic_load(pflag, __ATOMIC_ACQUIRE, __HIP_MEMORY_SCOPE_AGENT) < 2u * t + 1u)
        __builtin_amdgcn_s_sleep(1);
    }
    __syncthreads();
    if (tid < 128) {
      unsigned long long u = ld_rlx(pslot + tid);
      v2a[(1 - p) * 256 + tid * 2]     = unpack_lo(u);
      v2a[(1 - p) * 256 + tid * 2 + 1] = unpack_hi(u);
    }
    float r0, mu0;
    {
      unsigned long long u = ld_rlx(pslot + 128);
      float S = unpack_lo(u) + sq0own[0], Q = unpack_hi(u) + sq0own[1];
      mu0 = S * (1.f / HH);
      r0  = 1.f / sqrtf(Q * (1.f / HH) - mu0 * mu0 + 1e-5f);
    }
    if (tid < 256) h0prev = (v2own0 - mu0) * r0 * g0c + be0c;  // h0n^t (next residual)
    __syncthreads();                              // v2a full now

    mm512(accB2, wpi1, v2a, ksb);                 // h0n-input part
    *(float4*)&part[ks][oct * 8] = make_float4(
        r1p * accB[0] + r0 * accB2[0], r1p * accB[1] + r0 * accB2[1],
        r1p * accB[2] + r0 * accB2[2], r1p * accB[3] + r0 * accB2[3]);
    *(float4*)&part[ks][oct * 8 + 4] = make_float4(
        r1p * accB[4] + r0 * accB2[4], r1p * accB[5] + r0 * accB2[5],
        r1p * accB[6] + r0 * accB2[6], r1p * accB[7] + r0 * accB2[7]);
    r0p = r0; m0p = mu0;                          // becomes "prev" for next A
    __syncthreads();

    if (tid < 256) {
      float z = ((t == 0) ? c1i : c1f) - r0 * mu0 * uw1 - r1p * m1p * uh1;
#pragma unroll
      for (int i = 0; i < 16; ++i) z += part[i][c];
      float v21 = tanhf(z) + h1prev;
      v2own1 = v21;
      v2b[gc] = v21;
      float s = v21, q = v21 * v21;
#pragma unroll
      for (int off = 32; off; off >>= 1) { s += __shfl_down(s, off); q += __shfl_down(q, off); }
      if ((tid & 63) == 0) { wred[tid >> 6][0] = s; wred[tid >> 6][1] = q; }
    }
    __syncthreads();
    // publish exchange 1: v2_1 own half + (sum,sumsq)
    if (tid < 128) {
      st_rlx(myslot + 256 + tid, packf2(v2b[p * 256 + tid * 2], v2b[p * 256 + tid * 2 + 1]));
    }
    if (tid == 0) {
      float S = wred[0][0] + wred[1][0] + wred[2][0] + wred[3][0];
      float Q = wred[0][1] + wred[1][1] + wred[2][1] + wred[3][1];
      sq1own[0] = S; sq1own[1] = Q;
      st_rlx(myslot + 384, packf2(S, Q));
    }
    __syncthreads();
    if (tid == 0)
      __hip_atomic_store(myflag, 2u * t + 2u, __ATOMIC_RELEASE, __HIP_MEMORY_SCOPE_AGENT);
  }

  // ======== head: out[chain] = h1n . Wfc + bfc (even block only) ========
  if (p == 0) {
    if (tid == 0) {
      while (__hip_atomic_load(pflag, __ATOMIC_ACQUIRE, __HIP_MEMORY_SCOPE_AGENT) < 2u * T_SZ)
        __builtin_amdgcn_s_sleep(1);
    }
    __syncthreads();
    if (tid < 128) {
      unsigned long long u = ld_rlx(pslot + 256 + tid);
      v2b[256 + tid * 2]     = unpack_lo(u);
      v2b[256 + tid * 2 + 1] = unpack_hi(u);
    }
    float mu1, r1;
    {
      unsigned long long u = ld_rlx(pslot + 384);
      float S = unpack_lo(u) + sq1own[0], Q = unpack_hi(u) + sq1own[1];
      mu1 = S * (1.f / HH);
      r1  = 1.f / sqrtf(Q * (1.f / HH) - mu1 * mu1 + 1e-5f);
    }
    __syncthreads();
    float h = (v2b[tid] - mu1) * r1 * g1v[tid] + be1v[tid];
    float s = h * wfc[tid];
#pragma unroll
    for (int off = 32; off; off >>= 1) s += __shfl_down(s, off);
    if ((tid & 63) == 0) wredH[tid >> 6] = s;
    __syncthreads();
    if (tid == 0) {
      float S = 0.f;
#pragma unroll
      for (int w = 0; w < 8; ++w) S += wredH[w];
      out[chain] = S + bfc[0];
    }
  }
}

extern "C" void kernel_launch(void* const* d_in, const int* in_sizes, int n_in,
                              void* d_out, int out_size, void* d_ws, size_t ws_size,
                              hipStream_t stream) {
  const float* x   = (const float*)d_in[0];
  const float* Wi0 = (const float*)d_in[1];
  const float* bi0 = (const float*)d_in[2];
  const float* Wh0 = (const float*)d_in[3];
  const float* bh0 = (const float*)d_in[4];
  const float* g0  = (const float*)d_in[5];
  const float* be0 = (const float*)d_in[6];
  const float* Wi1 = (const float*)d_in[7];
  const float* bi1 = (const float*)d_in[8];
  const float* Wh1 = (const float*)d_in[9];
  const float* bh1 = (const float*)d_in[10];
  const float* g1  = (const float*)d_in[11];
  const float* be1 = (const float*)d_in[12];
  const float* Wfc = (const float*)d_in[13];
  const float* bfc = (const float*)d_in[14];
  float* out = (float*)d_out;

  // ws layout
  char* ws = (char*)d_ws;
  unsigned short* wi0b = (unsigned short*)(ws);                 //   64 KB
  unsigned short* wh0p = (unsigned short*)(ws + 65536);         //  512 KB
  unsigned short* wi1p = (unsigned short*)(ws + 589824);        //  512 KB
  unsigned short* wh1p = (unsigned short*)(ws + 1114112);       //  512 KB
  float* cvec          = (float*)(ws + 1638400);                //   14 KB (7 x 512 f32)
  unsigned long long* slots = (unsigned long long*)(ws + 1652736); // 256 x 4 KB = 1 MB
  unsigned* flags      = (unsigned*)(ws + 2701312);             //   32 KB

  prep_kernel<<<256, 256, 0, stream>>>(Wi0, Wh0, Wi1, Wh1, bi0, bh0, bi1, bh1,
                                       g0, be0, g1, be1,
                                       wi0b, wh0p, wi1p, wh1p, cvec, flags);
  rnn_pair<<<256, 512, 0, stream>>>(x, (const uint4*)wi0b, (const uint4*)wh0p,
                                    (const uint4*)wi1p, (const uint4*)wh1p,
                                    cvec, g0, be0, g1, be1, Wfc, bfc,
                                    slots, flags, out);
}